// Round 6
// baseline (55.448 us; speedup 1.0000x reference)
//
#include <hip/hip_runtime.h>
#include <hip/hip_bf16.h>

#define T_STEPS 128
#define BATCH   2048
#define IN_F    64
#define HID     256
#define OUT_F   16
#define CH      16                 // timesteps per group / staged x chunk
#define TROWS   16                 // batch rows per block (full M=16, no padding)
#define HHALF   128                // hid columns per block
#define NCHUNK  (T_STEPS / CH)     // 8 groups
#define SLAB    (BATCH * OUT_F)    // elems per timestep of g2 partials

typedef __attribute__((ext_vector_type(8))) short bf16x8;
typedef __attribute__((ext_vector_type(4))) float f32x4;
typedef unsigned short u16;
typedef unsigned int   u32;

__device__ __forceinline__ u16 f2bf(float f) {      // RNE via HW cvt (pk-fusable)
    union { __hip_bfloat16 h; u16 u; } cv;
    cv.h = __float2bfloat16(f);
    return cv.u;
}
__device__ __forceinline__ float bf2f(u16 h) {
    return __uint_as_float(((u32)h) << 16);
}
__device__ __forceinline__ bf16x8 pack8(float4 a, float4 b) {
    bf16x8 r;
    r[0] = (short)f2bf(a.x); r[1] = (short)f2bf(a.y);
    r[2] = (short)f2bf(a.z); r[3] = (short)f2bf(a.w);
    r[4] = (short)f2bf(b.x); r[5] = (short)f2bf(b.y);
    r[6] = (short)f2bf(b.z); r[7] = (short)f2bf(b.w);
    return r;
}

// Zero the spikes_mean accumulator (d_out not re-poisoned between replays).
__global__ void snn_init_kernel(float* __restrict__ out) {
    if (threadIdx.x == 0 && blockIdx.x == 0) out[BATCH * OUT_F] = 0.0f;
}

// Kernel 1: LIF layer, (16 rows x 128 hid) per block, 16 steps per barrier-pair.
// grid 256 = 128 row-tiles x 2 hid-halves (halves paired on the same XCD).
__global__ void __launch_bounds__(512, 2)
snn_l1_kernel(const float* __restrict__ x, const float* __restrict__ w1,
              const float* __restrict__ w2, u16* __restrict__ g2p,
              float* __restrict__ out)
{
    const int tid  = threadIdx.x;
    const int lane = tid & 63;
    const int wv   = tid >> 6;               // 8 waves
    const int hi   = lane >> 4;
    const int l15  = lane & 15;
    const int tile = blockIdx.x & 127;
    const int half = blockIdx.x >> 7;
    const int row0 = tile * TROWS;

    __shared__ __attribute__((aligned(16))) u16 xl[CH * TROWS * IN_F];    // 32 KB
    __shared__ __attribute__((aligned(16))) u16 zb[CH * TROWS * HHALF];   // 64 KB
    __shared__ float sacc;
    if (tid == 0) sacc = 0.f;

    const f32x4 zf = {0.f, 0.f, 0.f, 0.f};
    const float dt_tau = (float)(0.001 * (1.0 / 0.006));       // 1/6
    const float decay  = (float)(1.0 - 0.001 * (1.0 / 0.006)); // 5/6

    // W1 B-frags: col = half*128 + 16*wv + l15, k = 32kt + 8hi + i
    const int hcol = half * HHALF + wv * 16 + l15;
    bf16x8 w1f[2];
#pragma unroll
    for (int kt = 0; kt < 2; ++kt)
        w1f[kt] = pack8(*(const float4*)&w1[hcol * IN_F + kt * 32 + hi * 8],
                        *(const float4*)&w1[hcol * IN_F + kt * 32 + hi * 8 + 4]);

    // W2 B-frags (full local K=128): col = out = l15
    bf16x8 w2f[4];
#pragma unroll
    for (int kt = 0; kt < 4; ++kt) {
        const int k0 = half * HHALF + kt * 32 + hi * 8;
        w2f[kt] = pack8(*(const float4*)&w2[l15 * HID + k0],
                        *(const float4*)&w2[l15 * HID + k0 + 4]);
    }

    // ---- x staging map: 2048 bf16x8 vecs per chunk, 4 per thread ----
    int wofs[4];
    const float* gp[4];
    const size_t cstride = (size_t)CH * BATCH * IN_F;
#pragma unroll
    for (int j = 0; j < 4; ++j) {
        const int v  = tid + 512 * j;
        const int vs = v >> 7;            // step in chunk (0..15)
        const int vr = (v >> 3) & 15;     // row
        const int vk = (v & 7) * 8;       // k base (floats)
        wofs[j] = (vs * TROWS + vr) * IN_F + (vk ^ ((vr & 7) << 3));
        gp[j]   = x + ((size_t)vs * BATCH + row0 + vr) * IN_F + vk;
    }
    // prologue: chunk 0 -> LDS; chunk 1 -> regs (T14 split: write in phase C of g0)
    float4 ra[4], rb[4];
#pragma unroll
    for (int j = 0; j < 4; ++j) {
        ra[j] = *(const float4*)gp[j];
        rb[j] = *(const float4*)(gp[j] + 4);
        *(bf16x8*)&xl[wofs[j]] = pack8(ra[j], rb[j]);
    }
#pragma unroll
    for (int j = 0; j < 4; ++j) {
        ra[j] = *(const float4*)(gp[j] + cstride);
        rb[j] = *(const float4*)(gp[j] + cstride + 4);
    }

    f32x4 v1 = zf, i1 = zf;
    int wcnt = 0;                          // wave-uniform spike count (SALU)
    const int xswz = (l15 & 7) << 3;
    int zoff[4];
#pragma unroll
    for (int r = 0; r < 4; ++r) {
        const int zr = 4 * hi + r;
        zoff[r] = zr * HHALF + ((wv * 16 + l15) ^ ((zr & 15) << 3));
    }
    __syncthreads();

    for (int c = 0; c < NCHUNK; ++c) {
        // ---- phase A: g1 for all 16 steps, 32 independent MFMAs, no syncs ----
        f32x4 g1[CH];
#pragma unroll
        for (int s = 0; s < CH; ++s) {
            const u16* xrow = &xl[(s * TROWS + l15) * IN_F];
            const bf16x8 xf0 = *(const bf16x8*)(xrow + ((hi * 8) ^ xswz));
            const bf16x8 xf1 = *(const bf16x8*)(xrow + ((32 + hi * 8) ^ xswz));
            g1[s] = __builtin_amdgcn_mfma_f32_16x16x32_bf16(xf0, w1f[0], zf, 0, 0, 0);
            g1[s] = __builtin_amdgcn_mfma_f32_16x16x32_bf16(xf1, w1f[1], g1[s], 0, 0, 0);
        }

        // ---- phase B: 16-step LIF chain in registers; z -> swizzled LDS ----
#pragma unroll
        for (int s = 0; s < CH; ++s) {
            u16* zw = &zb[s * TROWS * HHALF];
            // vector forms -> packed v_pk_* fp32 ops
            const f32x4 vd = v1 + dt_tau * (i1 - v1);
            const f32x4 id = i1 * decay;
#pragma unroll
            for (int r = 0; r < 4; ++r) {
                const bool sp = vd[r] > 1.0f;
                v1[r] = sp ? 0.f : vd[r];
                wcnt += __popcll(__ballot(sp));        // SALU: s_bcnt1 + s_add
                zw[zoff[r]] = sp ? (u16)0x3F80 : (u16)0;
            }
            i1 = id + g1[s];
        }

        __syncthreads();   // barrier 1: z(group) published, xl reads complete

        // ---- phase C: stage x(c+1) into xl; issue loads for x(c+2) ----
        if (c + 1 < NCHUNK) {
#pragma unroll
            for (int j = 0; j < 4; ++j)
                *(bf16x8*)&xl[wofs[j]] = pack8(ra[j], rb[j]);
            if (c + 2 < NCHUNK) {
#pragma unroll
                for (int j = 0; j < 4; ++j) {
                    const float* g = gp[j] + 2 * cstride;
                    ra[j] = *(const float4*)g;
                    rb[j] = *(const float4*)(g + 4);
                    gp[j] += cstride;
                }
            }
        }

        // ---- phase C: wave wv computes g2 for steps wv and 8+wv ----
#pragma unroll
        for (int ss = 0; ss < 2; ++ss) {
            const int s = ss * 8 + wv;
            const u16* zr2 = &zb[(s * TROWS + l15) * HHALF];
            const int rsw = l15 << 3;
            const bf16x8 z0 = *(const bf16x8*)(zr2 + ((0 * 32 + hi * 8) ^ rsw));
            const bf16x8 z1 = *(const bf16x8*)(zr2 + ((1 * 32 + hi * 8) ^ rsw));
            const bf16x8 z2 = *(const bf16x8*)(zr2 + ((2 * 32 + hi * 8) ^ rsw));
            const bf16x8 z3 = *(const bf16x8*)(zr2 + ((3 * 32 + hi * 8) ^ rsw));
            f32x4 ga = __builtin_amdgcn_mfma_f32_16x16x32_bf16(z0, w2f[0], zf, 0, 0, 0);
            f32x4 gb = __builtin_amdgcn_mfma_f32_16x16x32_bf16(z1, w2f[1], zf, 0, 0, 0);
            ga = __builtin_amdgcn_mfma_f32_16x16x32_bf16(z2, w2f[2], ga, 0, 0, 0);
            gb = __builtin_amdgcn_mfma_f32_16x16x32_bf16(z3, w2f[3], gb, 0, 0, 0);
            const f32x4 g2 = ga + gb;
            u16* dst = g2p + (size_t)half * (T_STEPS * SLAB)
                     + (size_t)(c * CH + s) * SLAB + (row0 + 4 * hi) * OUT_F + l15;
#pragma unroll
            for (int r = 0; r < 4; ++r) dst[r * OUT_F] = f2bf(g2[r]);
        }

        __syncthreads();   // barrier 2: zb/xl free for next group
    }

    // spikes: wcnt is wave-uniform -> one LDS atomic per wave, one global atomic
    if (lane == 0) atomicAdd(&sacc, (float)wcnt);
    __syncthreads();
    if (tid == 0) atomicAdd(&out[BATCH * OUT_F], sacc * (1.0f / BATCH));
}

// Kernel 2: LI recurrence + max over t; one thread per (row, out) chain.
__global__ void __launch_bounds__(128)
snn_li_kernel(const u16* __restrict__ g2p, float* __restrict__ out)
{
    const int gid = blockIdx.x * 128 + threadIdx.x;    // 0..32767
    const u16* p0 = g2p + gid;
    const u16* p1 = g2p + (size_t)T_STEPS * SLAB + gid;
    const float dt_tau = (float)(0.001 * (1.0 / 0.006));
    const float decay  = (float)(1.0 - 0.001 * (1.0 / 0.006));
    float v2 = 0.f, i2 = 0.f, ymax = -1e30f;
#pragma unroll 8
    for (int t = 0; t < T_STEPS; ++t) {
        const float g = bf2f(p0[(size_t)t * SLAB]) + bf2f(p1[(size_t)t * SLAB]);
        v2 = fmaf(dt_tau, i2 - v2, v2);   // uses old i2, matches reference
        ymax = fmaxf(ymax, v2);
        i2 = i2 * decay + g;
    }
    out[gid] = ymax;
}

extern "C" void kernel_launch(void* const* d_in, const int* in_sizes, int n_in,
                              void* d_out, int out_size, void* d_ws, size_t ws_size,
                              hipStream_t stream) {
    const float* x  = (const float*)d_in[0];
    const float* w1 = (const float*)d_in[1];
    const float* w2 = (const float*)d_in[2];
    float* out = (float*)d_out;
    u16* g2p = (u16*)d_ws;   // 2 halves x 128 t x 32768 bf16 = 16 MB

    hipLaunchKernelGGL(snn_init_kernel, dim3(1), dim3(64), 0, stream, out);
    hipLaunchKernelGGL(snn_l1_kernel, dim3(256), dim3(512), 0, stream,
                       x, w1, w2, g2p, out);
    hipLaunchKernelGGL(snn_li_kernel, dim3(BATCH * OUT_F / 128), dim3(128), 0,
                       stream, g2p, out);
}